// Round 7
// baseline (3238.058 us; speedup 1.0000x reference)
//
#include <hip/hip_runtime.h>
#include <hip/hip_fp16.h>
#include <string.h>

// Problem constants (match reference)
constexpr int B = 64, T = 512, I = 512, H = 512, G = 2048; // G = 4*H

typedef _Float16 half8 __attribute__((ext_vector_type(8)));
typedef float floatx4 __attribute__((ext_vector_type(4)));

// ---------------------------------------------------------------------------
// Phase 1: xg[t][g][b] = sum_i x[b][t][i] * W_ih[g][i] + (b_ih[g] + b_hh[g])
// stored as f16. (unchanged from R5)
// ---------------------------------------------------------------------------
__global__ __launch_bounds__(256, 2) void xg_gemm(
    const float* __restrict__ x,     // [B][T][I]
    const float* __restrict__ W_ih,  // [G][I]
    const float* __restrict__ b_ih,
    const float* __restrict__ b_hh,
    _Float16* __restrict__ xg)       // [T][G][B]
{
    const int tid  = threadIdx.x;
    const int wave = tid >> 6, lane = tid & 63;
    const int quad = lane >> 4, col = lane & 15;
    const int rowA = blockIdx.x * 128 + wave * 16;
    const int rowB = rowA + 64;

    __shared__ __align__(16) _Float16 xs[64][264];

    half8 wfA[16], wfB[16];
    {
        const float* wpA = W_ih + (size_t)(rowA + col) * I;
        const float* wpB = W_ih + (size_t)(rowB + col) * I;
#pragma unroll
        for (int kc = 0; kc < 16; ++kc) {
            half8 vA, vB;
#pragma unroll
            for (int j = 0; j < 8; ++j) {
                vA[j] = (_Float16)wpA[kc * 32 + quad * 8 + j];
                vB[j] = (_Float16)wpB[kc * 32 + quad * 8 + j];
            }
            wfA[kc] = vA; wfB[kc] = vB;
        }
    }
    float biasA[4], biasB[4];
#pragma unroll
    for (int r = 0; r < 4; ++r) {
        biasA[r] = b_ih[rowA + quad * 4 + r] + b_hh[rowA + quad * 4 + r];
        biasB[r] = b_ih[rowB + quad * 4 + r] + b_hh[rowB + quad * 4 + r];
    }

    for (int ti = 0; ti < 4; ++ti) {
        const int t = blockIdx.y * 4 + ti;
        floatx4 accA[4], accB[4];
#pragma unroll
        for (int nt = 0; nt < 4; ++nt) {
            accA[nt] = (floatx4){0.f, 0.f, 0.f, 0.f};
            accB[nt] = (floatx4){0.f, 0.f, 0.f, 0.f};
        }

        for (int hfl = 0; hfl < 2; ++hfl) {
            __syncthreads();
#pragma unroll 4
            for (int c = 0; c < 16; ++c) {
                int idx = c * 256 + tid;
                int row = idx >> 6;
                int kk  = (idx & 63) * 4;
                const float4 v = *(const float4*)(x + ((size_t)row * T + t) * I + hfl * 256 + kk);
                xs[row][kk + 0] = (_Float16)v.x;
                xs[row][kk + 1] = (_Float16)v.y;
                xs[row][kk + 2] = (_Float16)v.z;
                xs[row][kk + 3] = (_Float16)v.w;
            }
            __syncthreads();
#pragma unroll
            for (int kc = 0; kc < 8; ++kc) {
#pragma unroll
                for (int nt = 0; nt < 4; ++nt) {
                    const half8 bfr = *(const half8*)&xs[nt * 16 + col][kc * 32 + quad * 8];
                    accA[nt] = __builtin_amdgcn_mfma_f32_16x16x32_f16(
                        wfA[hfl * 8 + kc], bfr, accA[nt], 0, 0, 0);
                    accB[nt] = __builtin_amdgcn_mfma_f32_16x16x32_f16(
                        wfB[hfl * 8 + kc], bfr, accB[nt], 0, 0, 0);
                }
            }
        }
#pragma unroll
        for (int nt = 0; nt < 4; ++nt) {
            int b = nt * 16 + col;
#pragma unroll
            for (int r = 0; r < 4; ++r) {
                xg[((size_t)t * G + rowA + quad * 4 + r) * B + b] = (_Float16)(accA[nt][r] + biasA[r]);
                xg[((size_t)t * G + rowB + quad * 4 + r) * B + b] = (_Float16)(accB[nt][r] + biasB[r]);
            }
        }
    }
}

// ---------------------------------------------------------------------------
// Phase 2: batch-partitioned persistent recurrence (R5 structure).
// 64 blocks x 256 threads; 4 batch-groups (bg=blk&3, 16 batches) x 16
// H-slices (hg=blk>>2, 32 h-indices). h via sc1 (LLC-coherent) relaxed
// atomics — the proven protocol.
// R7 sync change (only diff vs R5):
//   * per-block epoch FLAG (plain sc1 store, no RMW): 16 dwords in ONE
//     64B line per group -> stores pipeline, no RMW serialization.
//   * only WAVE 0 of each block polls the line (64 polling waves device-
//     wide, not 16k threads): lane reads qword (lane&7), exit on
//     __all(min >= epoch). Other waves wait at __syncthreads (no traffic).
//   * out stores + xg prefetch AFTER flag publish (off critical path).
// ---------------------------------------------------------------------------
__global__ __launch_bounds__(256, 1) void lstm_rec(
    const float* __restrict__ h0,    // [B][H]
    const float* __restrict__ c0,    // [B][H]
    const float* __restrict__ W_hh,  // [G][H]
    const _Float16* __restrict__ xg, // [T][G][B]
    _Float16* __restrict__ hbuf,     // [2][4][16][512] f16
    unsigned int* __restrict__ flags,// 64 dwords: group g -> flags[g*16+hg]
    float* __restrict__ out)         // [B][T][H] ++ hT[B][H] ++ cT[B][H]
{
    const int blk  = blockIdx.x;
    const int bg   = blk & 3;        // batch group (16 batches)
    const int hg   = blk >> 2;       // H slice (32 h-indices)
    const int tid  = threadIdx.x;
    const int wave = tid >> 6, lane = tid & 63;
    const int quad = lane >> 4, col = lane & 15;

    const int bglob = bg * 16 + col;       // this lane's batch (N = col)
    const int hbase = hg * 32 + wave * 8;  // this wave's 8 h-indices

    unsigned int* myflag = flags + bg * 16 + hg;
    const unsigned long long* fq = (const unsigned long long*)(flags + bg * 16); // 8 qwords

    // A-fragment rows (m = col): tile0 = [i(8), f(8)], tile1 = [g(8), o(8)]
    int arow0 = (col < 8) ? (hbase + col) : (512 + hbase + col - 8);
    int arow1 = arow0 + 1024;
    half8 wf0[16], wf1[16];
#pragma unroll
    for (int kc = 0; kc < 16; ++kc) {
        const float* p0 = W_hh + (size_t)arow0 * H + kc * 32 + quad * 8;
        const float* p1 = W_hh + (size_t)arow1 * H + kc * 32 + quad * 8;
        half8 v0, v1;
#pragma unroll
        for (int j = 0; j < 8; ++j) { v0[j] = (_Float16)p0[j]; v1[j] = (_Float16)p1[j]; }
        wf0[kc] = v0; wf1[kc] = v1;
    }

    // C rows this lane holds (lr = quad*4+r): xg row indices
    int xrow0[4], xrow1[4];
#pragma unroll
    for (int r = 0; r < 4; ++r) {
        int lr = quad * 4 + r;
        xrow0[r] = (lr < 8) ? (hbase + lr) : (512 + hbase + lr - 8);
        xrow1[r] = xrow0[r] + 1024;
    }

    // After xor-32 exchange this lane updates h-index hbase + (quad&1)*4 + r
    float c[4];
#pragma unroll
    for (int r = 0; r < 4; ++r)
        c[r] = c0[(size_t)bglob * H + hbase + (quad & 1) * 4 + r];

    // group h double buffer: hbuf[buf][bg][16][512]
    _Float16* hb0 = hbuf + ((size_t)0 * 4 + bg) * 16 * 512;
    _Float16* hb1 = hbuf + ((size_t)1 * 4 + bg) * 16 * 512;

    // ---- init: publish h0 into buf0, flag = 1 ----
    if (quad < 2) {
        _Float16 v4[4];
#pragma unroll
        for (int r = 0; r < 4; ++r)
            v4[r] = (_Float16)h0[(size_t)bglob * H + hbase + (quad & 1) * 4 + r];
        unsigned long long uv; __builtin_memcpy(&uv, v4, 8);
        __hip_atomic_store((unsigned long long*)(hb0 + (size_t)col * 512 + hbase + (quad & 1) * 4),
                           uv, __ATOMIC_RELAXED, __HIP_MEMORY_SCOPE_AGENT);
    }
    asm volatile("s_waitcnt vmcnt(0)" ::: "memory");
    __syncthreads();
    if (tid == 0)
        __hip_atomic_store(myflag, 1u, __ATOMIC_RELAXED, __HIP_MEMORY_SCOPE_AGENT);

    // prefetch xg for t=0 (plain cached loads; xg constant during phase 2)
    float xp0[4], xp1[4];
#pragma unroll
    for (int r = 0; r < 4; ++r) {
        xp0[r] = (float)xg[(size_t)xrow0[r] * B + bglob];
        xp1[r] = (float)xg[(size_t)xrow1[r] * B + bglob];
    }

    if (wave == 0) {
        for (;;) {
            unsigned long long v = __hip_atomic_load(fq + (lane & 7),
                                                     __ATOMIC_RELAXED, __HIP_MEMORY_SCOPE_AGENT);
            unsigned mn = min((unsigned)v, (unsigned)(v >> 32));
            if (__all(mn >= 1u)) break;
        }
    }
    __syncthreads();

    float hh[4] = {0.f, 0.f, 0.f, 0.f};

    for (int t = 0; t < T; ++t) {
        const _Float16* hcur = (t & 1) ? hb1 : hb0;
        _Float16*       hnxt = (t & 1) ? hb0 : hb1;

        // issue all coherent h loads first so they pipeline (one latency)
        unsigned long long hu0[16], hu1[16];
#pragma unroll
        for (int kc = 0; kc < 16; ++kc) {
            unsigned long long* hp =
                (unsigned long long*)(hcur + (size_t)col * 512 + kc * 32 + quad * 8);
            hu0[kc] = __hip_atomic_load(hp,     __ATOMIC_RELAXED, __HIP_MEMORY_SCOPE_AGENT);
            hu1[kc] = __hip_atomic_load(hp + 1, __ATOMIC_RELAXED, __HIP_MEMORY_SCOPE_AGENT);
        }

        floatx4 acc0 = (floatx4){0.f, 0.f, 0.f, 0.f};
        floatx4 acc1 = (floatx4){0.f, 0.f, 0.f, 0.f};
#pragma unroll
        for (int kc = 0; kc < 16; ++kc) {
            half8 bfr;
            __builtin_memcpy(&bfr, &hu0[kc], 8);
            __builtin_memcpy((char*)&bfr + 8, &hu1[kc], 8);
            acc0 = __builtin_amdgcn_mfma_f32_16x16x32_f16(wf0[kc], bfr, acc0, 0, 0, 0);
            acc1 = __builtin_amdgcn_mfma_f32_16x16x32_f16(wf1[kc], bfr, acc1, 0, 0, 0);
        }

        // add prefetched xg, exchange i/f and g/o halves across lane^32
        float p0[4], p1[4];
#pragma unroll
        for (int r = 0; r < 4; ++r) {
            p0[r] = acc0[r] + xp0[r];
            p1[r] = acc1[r] + xp1[r];
        }
        float e0[4], e1[4];
#pragma unroll
        for (int r = 0; r < 4; ++r) {
            e0[r] = __shfl_xor(p0[r], 32);
            e1[r] = __shfl_xor(p1[r], 32);
        }
#pragma unroll
        for (int r = 0; r < 4; ++r) {
            float iv = (quad < 2) ? p0[r] : e0[r];
            float fv = (quad < 2) ? e0[r] : p0[r];
            float gv = (quad < 2) ? p1[r] : e1[r];
            float ov = (quad < 2) ? e1[r] : p1[r];
            float ii = 1.f / (1.f + __expf(-iv));
            float ff = 1.f / (1.f + __expf(-fv));
            float eg = __expf(-2.f * gv);
            float gg = (1.f - eg) / (1.f + eg);
            float oo = 1.f / (1.f + __expf(-ov));
            float cn = ff * c[r] + ii * gg;
            c[r] = cn;
            float ec = __expf(-2.f * cn);
            hh[r] = oo * ((1.f - ec) / (1.f + ec));
        }

        // h store: one 8B agent-relaxed store (sc1 -> LLC)
        if (quad < 2) {
            _Float16 v4[4] = {(_Float16)hh[0], (_Float16)hh[1],
                              (_Float16)hh[2], (_Float16)hh[3]};
            unsigned long long uv; __builtin_memcpy(&uv, v4, 8);
            __hip_atomic_store((unsigned long long*)(hnxt + (size_t)col * 512 + hbase + (quad & 1) * 4),
                               uv, __ATOMIC_RELAXED, __HIP_MEMORY_SCOPE_AGENT);
        }

        // ---- drain h stores (and this step's h reads), publish epoch flag
        asm volatile("s_waitcnt vmcnt(0)" ::: "memory");
        __syncthreads();
        if (tid == 0)
            __hip_atomic_store(myflag, (unsigned)(t + 2),
                               __ATOMIC_RELAXED, __HIP_MEMORY_SCOPE_AGENT);

        // off the critical path: out store + xg prefetch for t+1
        if (quad < 2) {
            float* op = out + ((size_t)bglob * T + t) * H + hbase + (quad & 1) * 4;
            *(float4*)op = (float4){hh[0], hh[1], hh[2], hh[3]};
        }
        if (t + 1 < T) {
            const _Float16* xgt = xg + (size_t)(t + 1) * G * B;
#pragma unroll
            for (int r = 0; r < 4; ++r) {
                xp0[r] = (float)xgt[(size_t)xrow0[r] * B + bglob];
                xp1[r] = (float)xgt[(size_t)xrow1[r] * B + bglob];
            }
            // ---- wait: wave 0 polls the group's single flag line
            const unsigned tgt = (unsigned)(t + 2);
            if (wave == 0) {
                for (;;) {
                    unsigned long long v = __hip_atomic_load(fq + (lane & 7),
                                                             __ATOMIC_RELAXED, __HIP_MEMORY_SCOPE_AGENT);
                    unsigned mn = min((unsigned)v, (unsigned)(v >> 32));
                    if (__all(mn >= tgt)) break;
                }
            }
            __syncthreads();
        }
    }

    // final h_T, c_T
    if (quad < 2) {
        float* hT = out + (size_t)B * T * H;
        float* cT = hT + (size_t)B * H;
#pragma unroll
        for (int r = 0; r < 4; ++r) {
            int jj = (quad & 1) * 4 + r;
            hT[(size_t)bglob * H + hbase + jj] = hh[r];
            cT[(size_t)bglob * H + hbase + jj] = c[r];
        }
    }
}

// ---------------------------------------------------------------------------
extern "C" void kernel_launch(void* const* d_in, const int* in_sizes, int n_in,
                              void* d_out, int out_size, void* d_ws, size_t ws_size,
                              hipStream_t stream) {
    const float* x    = (const float*)d_in[0];
    const float* h0   = (const float*)d_in[1];
    const float* c0   = (const float*)d_in[2];
    const float* W_ih = (const float*)d_in[3];
    const float* W_hh = (const float*)d_in[4];
    const float* b_ih = (const float*)d_in[5];
    const float* b_hh = (const float*)d_in[6];
    float* out = (float*)d_out;

    // workspace layout:
    //   [0, 256)      : 64 epoch flags — group g owns flags[g*16..g*16+15]
    //                   (one 64B line per group), zeroed
    //   [2048, +128K) : h double buffer (f16) [2][4][16][512]
    //   [next, +128M) : xg (f16)
    unsigned int* flags = (unsigned int*)d_ws;
    _Float16* hbuf = (_Float16*)((char*)d_ws + 2048);
    _Float16* xg   = (_Float16*)((char*)d_ws + 2048 + (size_t)2 * 4 * 16 * 512 * 2);

    hipMemsetAsync(d_ws, 0, 2048, stream);

    xg_gemm<<<dim3(16, 128), 256, 0, stream>>>(x, W_ih, b_ih, b_hh, xg);
    lstm_rec<<<64, 256, 0, stream>>>(h0, c0, W_hh, xg, hbuf, flags, out);
}